// Round 14
// baseline (786.752 us; speedup 1.0000x reference)
//
#include <hip/hip_runtime.h>
#include <hip/hip_bf16.h>
#include <hip/hip_fp16.h>
#include <math.h>

#define NN 8192
#define HIDD 768
#define NCLS 18
#define OD 512          // HEADS*GD = 2*256
#define ETOT 342        // 324 class edges + 18 self loops
#define NEG 0.2f
#define LN_EPS 1e-5f

typedef __attribute__((ext_vector_type(8))) short bf16x8;
typedef __attribute__((ext_vector_type(4))) float f32x4;

// ---------- sorted top-5 insert (static indices, stays in registers) --------
__device__ __forceinline__ void top5_insert(float s, int idx,
    float& d0, float& d1, float& d2, float& d3, float& d4,
    int& i0, int& i1, int& i2, int& i3, int& i4) {
  if (s >= d4) return;
  if (s < d3) {
    d4 = d3; i4 = i3;
    if (s < d2) {
      d3 = d2; i3 = i2;
      if (s < d1) {
        d2 = d1; i2 = i1;
        if (s < d0) { d1 = d0; i1 = i0; d0 = s; i0 = idx; }
        else        { d1 = s;  i1 = idx; }
      } else { d2 = s; i2 = idx; }
    } else { d3 = s; i3 = idx; }
  } else { d4 = s; i4 = idx; }
}

// ---------- top-8 insert on packed u32 keys (rank-based, static indices) ----
__device__ __forceinline__ void top8k_insert(unsigned key, unsigned (&kk)[8]) {
  if (key >= kk[7]) return;
  int rank = 0;
  #pragma unroll
  for (int k = 0; k < 7; ++k) rank += (key >= kk[k]) ? 1 : 0;
  #pragma unroll
  for (int k = 7; k >= 1; --k) if (k > rank) kk[k] = kk[k-1];
  #pragma unroll
  for (int k = 0; k < 8; ++k) if (k == rank) kk[k] = key;
}

// ---------- async global->LDS 16B (used only in gemm_nt_mfma) ---------------
__device__ __forceinline__ void stage16(const void* g, void* l) {
  __builtin_amdgcn_global_load_lds(
      (const __attribute__((address_space(1))) unsigned int*)g,
      (__attribute__((address_space(3))) unsigned int*)l, 16, 0, 0);
}

__device__ __forceinline__ ushort f2b(float v) {
  __hip_bfloat16 b = __float2bfloat16(v);
  return *(ushort*)&b;
}
__device__ __forceinline__ float b2f(ushort u) {
  unsigned uv = ((unsigned)u) << 16;
  return *(float*)&uv;
}

// ============ prep1 mega-kernel: independent preamble tasks ==================
__global__ __launch_bounds__(256) void prep1_kernel(
    const float* __restrict__ X, ushort* __restrict__ Xh, float* __restrict__ x2,
    const float* __restrict__ gi_wl, const float* __restrict__ gi_wr,
    ushort* __restrict__ wlrh,
    const float* __restrict__ cemb, const float* __restrict__ gc_wl,
    const float* __restrict__ gc_bl, const float* __restrict__ gc_wr,
    const float* __restrict__ gc_br, float* __restrict__ xlc, float* __restrict__ xrc,
    const float* __restrict__ wv, const float* __restrict__ ctx_b,
    const float* __restrict__ bv, float* __restrict__ t1b,
    const float* __restrict__ gi_bl, const float* __restrict__ gi_br,
    float* __restrict__ bb) {
  const int bx = blockIdx.x, tid = threadIdx.x;
  if (bx < 2048) {                       // ---- rowcast + rownorm ----
    const int row = bx * 4 + (tid >> 6);
    const int lane = tid & 63;
    const float4* src = (const float4*)(X + (size_t)row * HIDD);
    ushort4* dst = (ushort4*)(Xh + (size_t)row * HIDD);
    float s = 0.f;
    #pragma unroll
    for (int q = 0; q < 3; ++q) {
      float4 v = src[lane + q * 64];
      s += v.x * v.x + v.y * v.y + v.z * v.z + v.w * v.w;
      dst[lane + q * 64] = make_ushort4(f2b(v.x), f2b(v.y), f2b(v.z), f2b(v.w));
    }
    #pragma unroll
    for (int off = 32; off; off >>= 1) s += __shfl_down(s, off);
    if (lane == 0) x2[row] = s;
  } else if (bx < 2816) {                // ---- weight casts ----
    int rel = bx - 2048;
    const float* src = gi_wl; ushort* dst = wlrh;
    if (rel >= 384) { rel -= 384; src = gi_wr; dst = wlrh + (size_t)OD * HIDD; }
    const int i = rel * 256 + tid;       // < 98304 = OD*HIDD/4
    float4 v = ((const float4*)src)[i];
    ((ushort4*)dst)[i] = make_ushort4(f2b(v.x), f2b(v.y), f2b(v.z), f2b(v.w));
  } else if (bx < 2888) {                // ---- class xlc/xrc (float4) ----
    int t = (bx - 2816) * 256 + tid;
    const float* W; const float* b; float* Y;
    if (t < NCLS * OD) { W = gc_wl; b = gc_bl; Y = xlc; }
    else { t -= NCLS * OD; W = gc_wr; b = gc_br; Y = xrc; }
    const int row = t / OD, o = t - row * OD;
    const float4* xr4 = (const float4*)(cemb + (size_t)row * HIDD);
    const float4* wr4 = (const float4*)(W + (size_t)o * HIDD);
    float acc = 0.f;
    for (int k = 0; k < HIDD / 4; ++k) {
      const float4 a = xr4[k], w4 = wr4[k];
      acc += a.x * w4.x + a.y * w4.y + a.z * w4.z + a.w * w4.w;
    }
    Y[t] = acc + b[o];
  } else if (bx < 2891) {                // ---- t1b (float4) ----
    const int t = (bx - 2888) * 256 + tid;
    if (t < HIDD) {
      const float4* cb4 = (const float4*)ctx_b;
      const float4* wv4 = (const float4*)(wv + (size_t)t * HIDD);
      float acc = 0.f;
      for (int k = 0; k < HIDD / 4; ++k) {
        const float4 a = cb4[k], w4 = wv4[k];
        acc += a.x * w4.x + a.y * w4.y + a.z * w4.z + a.w * w4.w;
      }
      t1b[t] = acc + bv[t];
    }
  } else {                               // ---- bias stack ----
    const int t = (bx - 2891) * 256 + tid;
    if (t < OD) bb[t] = gi_bl[t];
    else if (t < 2 * OD) bb[t] = gi_br[t - OD];
  }
}

// ============ tiled fp32 NN GEMM: C[M,N] = A[M,K] @ B[K,N] ===================
__global__ __launch_bounds__(256) void gemm_nn_f32(const float* __restrict__ A,
    const float* __restrict__ B, float* __restrict__ Cf, ushort* __restrict__ Ch,
    int M, int N, int K) {
  __shared__ float As[64][33];
  __shared__ float Bs[32][65];
  const int tid = threadIdx.x, tx = tid & 15, ty = tid >> 4;
  const int r0 = blockIdx.x * 64, c0 = blockIdx.y * 64;
  float acc[4][4] = {};
  for (int kt = 0; kt < K; kt += 32) {
    __syncthreads();
    #pragma unroll
    for (int l = 0; l < 8; ++l) {
      const int idx = l * 256 + tid;
      const int m = idx >> 5, k = idx & 31;
      As[m][k] = A[(size_t)(r0 + m) * K + kt + k];
      const int k2 = idx >> 6, n = idx & 63;
      Bs[k2][n] = B[(size_t)(kt + k2) * N + c0 + n];
    }
    __syncthreads();
    #pragma unroll
    for (int k = 0; k < 32; ++k) {
      float a[4], b[4];
      #pragma unroll
      for (int i = 0; i < 4; ++i) a[i] = As[ty * 4 + i][k];
      #pragma unroll
      for (int j = 0; j < 4; ++j) b[j] = Bs[k][tx * 4 + j];
      #pragma unroll
      for (int i = 0; i < 4; ++i)
        #pragma unroll
        for (int j = 0; j < 4; ++j) acc[i][j] += a[i] * b[j];
    }
  }
  #pragma unroll
  for (int i = 0; i < 4; ++i) {
    const int r = r0 + ty * 4 + i;
    #pragma unroll
    for (int j = 0; j < 4; ++j) {
      const int c = c0 + tx * 4 + j;
      if (Ch) Ch[(size_t)r * N + c] = f2b(acc[i][j]);
      else    Cf[(size_t)r * N + c] = acc[i][j];
    }
  }
}

// ============ prep2: bp (float4) + class-graph GAT ===========================
__global__ __launch_bounds__(256) void prep2_kernel(
    const float* __restrict__ wo, const float* __restrict__ t1b,
    const float* __restrict__ bo, float* __restrict__ bp,
    const int* __restrict__ cei, const float* __restrict__ xlc,
    const float* __restrict__ xrc, const float* __restrict__ gc_att,
    const float* __restrict__ gc_bias, float* __restrict__ cmean) {
  __shared__ float sc[ETOT * 2];
  __shared__ int es[ETOT], ed[ETOT];
  __shared__ float mx[NCLS][2], sm[NCLS][2];
  const int bx = blockIdx.x, tid = threadIdx.x;
  if (bx < 3) {                          // ---- bp ----
    const int t = bx * 256 + tid;
    if (t < HIDD) {
      const float4* tb4 = (const float4*)t1b;
      const float4* wo4 = (const float4*)(wo + (size_t)t * HIDD);
      float acc = 0.f;
      for (int k = 0; k < HIDD / 4; ++k) {
        const float4 a = tb4[k], w4 = wo4[k];
        acc += a.x * w4.x + a.y * w4.y + a.z * w4.z + a.w * w4.w;
      }
      bp[t] = acc + bo[t];
    }
  } else {                               // ---- class GAT (1 block) ----
    for (int e = tid; e < ETOT; e += 256) {
      if (e < 324) { es[e] = cei[e]; ed[e] = cei[324 + e]; }
      else         { es[e] = e - 324; ed[e] = e - 324; }
    }
    __syncthreads();
    const int lane = tid & 63, w = tid >> 6;
    for (int t = w; t < ETOT * 2; t += 4) {
      const int e = t >> 1, h = t & 1;
      const float* xlr = xlc + (size_t)es[e] * OD + h * 256;
      const float* xrr = xrc + (size_t)ed[e] * OD + h * 256;
      const float* ar  = gc_att + h * 256;
      float s = 0.f;
      for (int d = lane; d < 256; d += 64) {
        float v = xlr[d] + xrr[d];
        v = v > 0.f ? v : NEG * v;
        s += v * ar[d];
      }
      #pragma unroll
      for (int off = 32; off; off >>= 1) s += __shfl_down(s, off);
      if (lane == 0) sc[t] = s;
    }
    __syncthreads();
    if (tid < NCLS * 2) {
      const int d = tid >> 1, h = tid & 1;
      float m = -3e38f;
      for (int e = 0; e < ETOT; ++e) if (ed[e] == d) m = fmaxf(m, sc[e * 2 + h]);
      float ssum = 0.f;
      for (int e = 0; e < ETOT; ++e) if (ed[e] == d) ssum += expf(sc[e * 2 + h] - m);
      mx[d][h] = m; sm[d][h] = 1.f / ssum;
    }
    __syncthreads();
    for (int t = tid; t < ETOT * 2; t += 256) {
      const int e = t >> 1, h = t & 1;
      sc[t] = expf(sc[t] - mx[ed[e]][h]) * sm[ed[e]][h];
    }
    __syncthreads();
    for (int c = tid; c < OD; c += 256) {
      const int h = c >> 8;
      float acc = 0.f;
      for (int e = 0; e < ETOT; ++e) acc += sc[e * 2 + h] * xlc[(size_t)es[e] * OD + c];
      cmean[c] = acc * (1.f / 18.f) + gc_bias[c];
    }
  }
}

// ---------- stage 1: SYMMETRIC bf16 MFMA distances (VERBATIM round-11 scan) --
// One block per upper-triangle 128x128 tile (bx<=by): compute -2*A_i·B_j^T
// once, scan BOTH ways. Dh stores f16(-2*dot); keys built in-scan (proven).
// pck layout: [row][64 groups][8] u32 keys (monotone-f16(score-768)<<16 | col).
__global__ __launch_bounds__(256, 4) void dist_sym_mfma(
    const ushort* __restrict__ Xh, const float* __restrict__ x2,
    unsigned* __restrict__ pck) {
  __shared__ __align__(16) char lds[32768];   // sA|sB staging ∪ Dh scores ∪ ck
  __shared__ float x2i[128], x2j[128];
  char* const sA = lds;
  char* const sB = lds + 16384;
  __half* const Dh = (__half*)lds;            // [128][128] f16 (-2*dot), rotated
  unsigned* const ck = (unsigned*)lds;        // merge [256][8] u32

  // triangular decode: t -> (bx, by) with bx <= by
  const int t = blockIdx.x;
  int by = (int)((sqrtf(8.0f * (float)t + 1.0f) - 1.0f) * 0.5f);
  while ((by + 1) * (by + 2) / 2 <= t) ++by;
  while (by * (by + 1) / 2 > t) --by;
  const int bx = t - by * (by + 1) / 2;

  const int tid = threadIdx.x;
  const int lane = tid & 63, wid = tid >> 6;
  const int fr = lane & 15, fq = lane >> 4;
  const int i0 = bx * 128, j0 = by * 128;
  const int wr = (wid >> 1) * 64, wc = (wid & 1) * 64;
  const bool diag = (bx == by);

  if (tid < 128) x2i[tid] = x2[i0 + tid];
  else x2j[tid - 128] = x2[j0 + tid - 128];

  f32x4 acc[4][4] = {};
  for (int kt = 0; kt < HIDD; kt += 64) {
    __syncthreads();                       // prior LDS readers done
    #pragma unroll
    for (int q = 0; q < 4; ++q) {
      const int chunkid = q * 256 + tid;
      const int row = chunkid >> 3, cc = chunkid & 7;
      const bf16x8 va = *(const bf16x8*)(Xh + (size_t)(i0 + row) * HIDD + kt + cc * 8);
      const bf16x8 vb = *(const bf16x8*)(Xh + (size_t)(j0 + row) * HIDD + kt + cc * 8);
      const int wi = row * 128 + ((cc ^ (row & 7)) << 4);
      *(bf16x8*)(sA + wi) = va;
      *(bf16x8*)(sB + wi) = vb;
    }
    __syncthreads();                       // staged data visible
    #pragma unroll
    for (int kk = 0; kk < 2; ++kk) {
      bf16x8 bh[4];
      #pragma unroll
      for (int n = 0; n < 4; ++n) {
        const int br = wc + n * 16 + fr;
        bh[n] = *(const bf16x8*)(sB + br * 128 + (((kk * 4 + fq) ^ (br & 7)) << 4));
      }
      #pragma unroll
      for (int m = 0; m < 4; ++m) {
        const int ar = wr + m * 16 + fr;
        const bf16x8 a = *(const bf16x8*)(sA + ar * 128 + (((kk * 4 + fq) ^ (ar & 7)) << 4));
        #pragma unroll
        for (int n = 0; n < 4; ++n)
          acc[m][n] = __builtin_amdgcn_mfma_f32_16x16x32_bf16(a, bh[n], acc[m][n], 0, 0, 0);
      }
    }
  }
  __syncthreads();                         // all frag reads done; overlay Dh
  // store f16(-2*dot), col slot rotated by row (row AND col reads conflict-light)
  #pragma unroll
  for (int n = 0; n < 4; ++n) {
    const int col = wc + n * 16 + fr;
    #pragma unroll
    for (int m = 0; m < 4; ++m) {
      #pragma unroll
      for (int j = 0; j < 4; ++j) {
        const int row = wr + m * 16 + fq * 4 + j;
        Dh[row * 128 + ((col + row) & 127)] = __float2half(-2.0f * acc[m][n][j]);
      }
    }
  }
  __syncthreads();

  unsigned ki[8], kj[8];
  #pragma unroll
  for (int k = 0; k < 8; ++k) { ki[k] = 0xFFFFFFFFu; kj[k] = 0xFFFFFFFFu; }
  const int r = tid & 127, h = tid >> 7;
  // phase-1 scan: rows-of-i over cols-of-j
  for (int c = 0; c < 64; ++c) {
    const int col = h * 64 + c;
    const float s = x2j[col] - 768.0f + __half2float(Dh[r * 128 + ((col + r) & 127)]);
    const ushort u = __half_as_ushort(__float2half(s));
    const ushort k16 = (u & 0x8000) ? (ushort)(~u) : (ushort)(u | 0x8000);
    top8k_insert(((unsigned)k16 << 16) | (unsigned)(j0 + col), ki);
  }
  // phase-2 scan: rows-of-j over cols-of-i (transpose read of Dh)
  if (!diag) {
    for (int c = 0; c < 64; ++c) {
      const int cr = h * 64 + c;
      const float s = x2i[cr] - 768.0f + __half2float(Dh[cr * 128 + ((r + cr) & 127)]);
      const ushort u = __half_as_ushort(__float2half(s));
      const ushort k16 = (u & 0x8000) ? (ushort)(~u) : (ushort)(u | 0x8000);
      top8k_insert(((unsigned)k16 << 16) | (unsigned)(i0 + cr), kj);
    }
  }
  __syncthreads();                         // Dh dead; ck may overlay
  // merge + write phase-1 lists: pck[(i0+r)][grp=by]
  #pragma unroll
  for (int k = 0; k < 8; ++k) ck[tid * 8 + k] = ki[k];
  __syncthreads();
  if (tid < 128) {
    unsigned mk[8];
    #pragma unroll
    for (int k = 0; k < 8; ++k) mk[k] = ck[tid * 8 + k];
    #pragma unroll
    for (int k = 0; k < 8; ++k) top8k_insert(ck[(tid + 128) * 8 + k], mk);
    const size_t base = ((size_t)(i0 + tid) * 64 + by) * 8;
    #pragma unroll
    for (int k = 0; k < 8; ++k) pck[base + k] = mk[k];
  }
  if (!diag) {                             // merge + write phase-2 lists
    __syncthreads();
    #pragma unroll
    for (int k = 0; k < 8; ++k) ck[tid * 8 + k] = kj[k];
    __syncthreads();
    if (tid < 128) {
      unsigned mk[8];
      #pragma unroll
      for (int k = 0; k < 8; ++k) mk[k] = ck[tid * 8 + k];
      #pragma unroll
      for (int k = 0; k < 8; ++k) top8k_insert(ck[(tid + 128) * 8 + k], mk);
      const size_t base = ((size_t)(j0 + tid) * 64 + bx) * 8;
      #pragma unroll
      for (int k = 0; k < 8; ++k) pck[base + k] = mk[k];
    }
  }
}

// ---------- fused: butterfly merge + exact refine + GATv2 aggregate ----------
__global__ __launch_bounds__(256) void mr_gat_kernel(
    const float* __restrict__ X, const float* __restrict__ x2,
    const unsigned* __restrict__ pck, const ushort* __restrict__ xlrh,
    const float* __restrict__ att, const float* __restrict__ bias,
    const float* __restrict__ cmean, ushort* __restrict__ ctxh) {
  __shared__ float rows[7][512];
  __shared__ float rsc[8];
  __shared__ int rcand[8];
  __shared__ int nbr[6];
  __shared__ float sc[12];
  __shared__ float alpha[12];
  const int i = blockIdx.x;
  const int tid = threadIdx.x;
  const int lane = tid & 63, w = tid >> 6;

  if (w == 0) {                            // merge 64 per-tile top-8 lists
    unsigned mk[8];
    #pragma unroll
    for (int k = 0; k < 8; ++k) mk[k] = pck[(size_t)i * 512 + lane * 8 + k];
    #pragma unroll
    for (int st = 1; st < 64; st <<= 1) {
      unsigned ok[8];
      #pragma unroll
      for (int k = 0; k < 8; ++k) ok[k] = __shfl_xor(mk[k], st);
      #pragma unroll
      for (int k = 0; k < 8; ++k) top8k_insert(ok[k], mk);
    }
    if (lane < 8) rcand[lane] = (int)(mk[lane] & 0xFFFFu);
  } else {                                 // preload self xl (rows[5]) + xr (rows[6])
    const int tt = tid - 64;
    if (tt < 128) {
      const int rr = 5 + (tt >> 6), e4 = tt & 63;
      const bf16x8 v = *(const bf16x8*)(xlrh + (size_t)i * 1024 + (rr == 6 ? 512 : 0) + e4 * 8);
      #pragma unroll
      for (int j = 0; j < 8; ++j) rows[rr][e4 * 8 + j] = b2f((ushort)v[j]);
    }
  }
  __syncthreads();
  // exact fp32 refine: wave w handles candidates 2w (lanes 0-31) and 2w+1
  {
    const int cnd = w * 2 + (lane >> 5);
    const int sl = lane & 31;
    const int cidx = rcand[cnd];
    const float4* xi = (const float4*)(X + (size_t)i * HIDD);
    const float4* xc = (const float4*)(X + (size_t)cidx * HIDD);
    float acc = 0.f;
    #pragma unroll
    for (int q = 0; q < 6; ++q) {
      const float4 a = xi[sl + q * 32];
      const float4 b = xc[sl + q * 32];
      acc += a.x * b.x + a.y * b.y + a.z * b.z + a.w * b.w;
    }
    #pragma unroll
    for (int off = 16; off; off >>= 1) acc += __shfl_down(acc, off, 32);
    if (sl == 0) rsc[cnd] = x2[cidx] - 2.0f * acc;
  }
  __syncthreads();
  if (tid == 0) {                          // exact top-5 of the 8 candidates
    float d0 = 3e38f, d1 = 3e38f, d2 = 3e38f, d3 = 3e38f, d4 = 3e38f;
    int i0 = 0, i1 = 0, i2 = 0, i3 = 0, i4 = 0;
    #pragma unroll
    for (int k = 0; k < 8; ++k)
      top5_insert(rsc[k], rcand[k], d0, d1, d2, d3, d4, i0, i1, i2, i3, i4);
    nbr[0] = i0; nbr[1] = i1; nbr[2] = i2; nbr[3] = i3; nbr[4] = i4; nbr[5] = i;
  }
  __syncthreads();
  // gather 5 neighbor xl rows (bf16): 320 slots over 256 threads -> strided loop
  for (int t2 = tid; t2 < 5 * 64; t2 += 256) {
    const int rr = t2 >> 6, e4 = t2 & 63;
    const bf16x8 v = *(const bf16x8*)(xlrh + (size_t)nbr[rr] * 1024 + e4 * 8);
    #pragma unroll
    for (int j = 0; j < 8; ++j) rows[rr][e4 * 8 + j] = b2f((ushort)v[j]);
  }
  __syncthreads();
  // GATv2 scores (12 tasks over 4 waves)
  for (int t = w; t < 12; t += 4) {
    const int e = t >> 1, h = t & 1;
    const float* ar = att + h * 256;
    float s = 0.f;
    #pragma unroll
    for (int q = 0; q < 4; ++q) {
      const int d = lane + q * 64;
      float v = rows[e][h * 256 + d] + rows[6][h * 256 + d];
      v = v > 0.f ? v : NEG * v;
      s += v * ar[d];
    }
    #pragma unroll
    for (int off = 32; off; off >>= 1) s += __shfl_down(s, off);
    if (lane == 0) sc[t] = s;
  }
  __syncthreads();
  if (tid < 2) {
    const int h = tid;
    float m = -3e38f;
    #pragma unroll
    for (int e = 0; e < 6; ++e) m = fmaxf(m, sc[e * 2 + h]);
    float ssum = 0.f;
    #pragma unroll
    for (int e = 0; e < 6; ++e) { float ex = expf(sc[e * 2 + h] - m); alpha[e * 2 + h] = ex; ssum += ex; }
    const float inv = 1.f / ssum;
    #pragma unroll
    for (int e = 0; e < 6; ++e) alpha[e * 2 + h] *= inv;
  }
  __syncthreads();
  for (int c = tid; c < OD; c += 256) {
    const int h = c >> 8;
    float acc = 0.f;
    #pragma unroll
    for (int e = 0; e < 6; ++e) acc += alpha[e * 2 + h] * rows[e][c];
    ctxh[(size_t)i * OD + c] = f2b(acc + bias[c] + cmean[c]);
  }
}

// ---------- bf16 MFMA GEMM: C = A @ B^T + bias (f32 or bf16 output) ----------
__global__ __launch_bounds__(256) void gemm_nt_mfma(const ushort* __restrict__ A,
    const ushort* __restrict__ B, const float* __restrict__ bias,
    float* __restrict__ C, ushort* __restrict__ Cb, int Nc, int K) {
  __shared__ char lds[32768];
  char* const pA = lds;
  char* const pB = lds + 16384;
  const int tid = threadIdx.x;
  const int lane = tid & 63, wid = tid >> 6;
  const int fr = lane & 15, fq = lane >> 4;
  const int r0 = blockIdx.x * 128;
  const int c0 = blockIdx.y * 128;
  const int wr = (wid >> 1) * 64, wc = (wid & 1) * 64;
  f32x4 acc[4][4] = {};
  for (int kt = 0; kt < K; kt += 64) {
    __syncthreads();
    #pragma unroll
    for (int q = 0; q < 4; ++q) {
      const int chunk = wid * 256 + q * 64 + lane;
      const int row = chunk >> 3;
      const int lc = (chunk & 7) ^ (row & 7);
      const int ld = wid * 4096 + q * 1024;
      stage16((const char*)A + ((size_t)(r0 + row) * K + kt) * 2 + (size_t)lc * 16, pA + ld);
      stage16((const char*)B + ((size_t)(c0 + row) * K + kt) * 2 + (size_t)lc * 16, pB + ld);
    }
    __syncthreads();
    #pragma unroll
    for (int kk = 0; kk < 2; ++kk) {
      bf16x8 ah[4], bh[4];
      #pragma unroll
      for (int m = 0; m < 4; ++m) {
        const int ar = wr + m * 16 + fr;
        ah[m] = *(const bf16x8*)(pA + ar * 128 + (((kk * 4 + fq) ^ (ar & 7)) << 4));
      }
      #pragma unroll
      for (int n = 0; n < 4; ++n) {
        const int br = wc + n * 16 + fr;
        bh[n] = *(const bf16x8*)(pB + br * 128 + (((kk * 4 + fq) ^ (br & 7)) << 4));
      }
      #pragma unroll
      for (int m = 0; m < 4; ++m)
        #pragma unroll
        for (int n = 0; n < 4; ++n)
          acc[m][n] = __builtin_amdgcn_mfma_f32_16x16x32_bf16(ah[m], bh[n], acc[m][n], 0, 0, 0);
    }
  }
  #pragma unroll
  for (int n = 0; n < 4; ++n) {
    const int cc = c0 + wc + n * 16 + fr;
    const float bs = bias[cc];
    #pragma unroll
    for (int m = 0; m < 4; ++m) {
      #pragma unroll
      for (int j = 0; j < 4; ++j) {
        const int rr = r0 + wr + m * 16 + fq * 4 + j;
        const float val = acc[m][n][j] + bs;
        if (Cb) Cb[(size_t)rr * Nc + cc] = f2b(val);
        else    C[(size_t)rr * Nc + cc] = val;
      }
    }
  }
}

// ---------- fused epilogue: LN1 -> LN2 -> GELU -> 18-way classifier ----------
__global__ __launch_bounds__(256) void epilogue_kernel(const float* __restrict__ inst,
    const float* __restrict__ attn, const float* __restrict__ g1, const float* __restrict__ b1,
    const float* __restrict__ g2, const float* __restrict__ b2, const float* __restrict__ gw,
    const float* __restrict__ gb, const float* __restrict__ temp, float* __restrict__ out) {
  __shared__ float buf[HIDD];
  __shared__ float red[4];
  const int i = blockIdx.x;
  const int tid = threadIdx.x;
  const int lane = tid & 63, w = tid >> 6;
  size_t base = (size_t)i * HIDD;
  float v0 = inst[base + tid]       + attn[base + tid];
  float v1 = inst[base + tid + 256] + attn[base + tid + 256];
  float v2 = inst[base + tid + 512] + attn[base + tid + 512];

  float s = v0 + v1 + v2;
  #pragma unroll
  for (int off = 32; off; off >>= 1) s += __shfl_down(s, off);
  if (lane == 0) red[w] = s;
  __syncthreads();
  float mean = (red[0] + red[1] + red[2] + red[3]) * (1.f / HIDD);
  __syncthreads();
  float e0 = v0 - mean, e1 = v1 - mean, e2 = v2 - mean;
  s = e0 * e0 + e1 * e1 + e2 * e2;
  #pragma unroll
  for (int off = 32; off; off >>= 1) s += __shfl_down(s, off);
  if (lane == 0) red[w] = s;
  __syncthreads();
  float rstd = rsqrtf((red[0] + red[1] + red[2] + red[3]) * (1.f / HIDD) + LN_EPS);
  __syncthreads();
  float y0 = e0 * rstd * g1[tid]       + b1[tid];
  float y1 = e1 * rstd * g1[tid + 256] + b1[tid + 256];
  float y2 = e2 * rstd * g1[tid + 512] + b1[tid + 512];

  s = y0 + y1 + y2;
  #pragma unroll
  for (int off = 32; off; off >>= 1) s += __shfl_down(s, off);
  if (lane == 0) red[w] = s;
  __syncthreads();
  float mean2 = (red[0] + red[1] + red[2] + red[3]) * (1.f / HIDD);
  __syncthreads();
  float f0 = y0 - mean2, f1 = y1 - mean2, f2 = y2 - mean2;
  s = f0 * f0 + f1 * f1 + f2 * f2;
  #pragma unroll
  for (int off = 32; off; off >>= 1) s += __shfl_down(s, off);
  if (lane == 0) red[w] = s;
  __syncthreads();
  float rstd2 = rsqrtf((red[0] + red[1] + red[2] + red[3]) * (1.f / HIDD) + LN_EPS);
  float z0 = f0 * rstd2 * g2[tid]       + b2[tid];
  float z1 = f1 * rstd2 * g2[tid + 256] + b2[tid + 256];
  float z2 = f2 * rstd2 * g2[tid + 512] + b2[tid + 512];
  buf[tid]       = 0.5f * z0 * (1.f + erff(z0 * 0.70710678118654752f));
  buf[tid + 256] = 0.5f * z1 * (1.f + erff(z1 * 0.70710678118654752f));
  buf[tid + 512] = 0.5f * z2 * (1.f + erff(z2 * 0.70710678118654752f));
  __syncthreads();

  float invT = 1.f / temp[0];
  for (int c = w; c < NCLS; c += 4) {
    const float* wr = gw + (size_t)c * HIDD;
    float acc = 0.f;
    for (int d = lane; d < HIDD; d += 64) acc += buf[d] * wr[d];
    #pragma unroll
    for (int off = 32; off; off >>= 1) acc += __shfl_down(acc, off);
    if (lane == 0) out[(size_t)i * NCLS + c] = (acc + gb[c]) * invT;
  }
}

// ---------------------------------------------------------------------------
extern "C" void kernel_launch(void* const* d_in, const int* in_sizes, int n_in,
                              void* d_out, int out_size, void* d_ws, size_t ws_size,
                              hipStream_t stream) {
  (void)in_sizes; (void)n_in; (void)out_size; (void)ws_size;
  const float* X       = (const float*)d_in[0];
  const int*   cei     = (const int*)  d_in[1];
  const float* cemb    = (const float*)d_in[2];
  const float* gc_wl   = (const float*)d_in[3];
  const float* gc_bl   = (const float*)d_in[4];
  const float* gc_wr   = (const float*)d_in[5];
  const float* gc_br   = (const float*)d_in[6];
  const float* gc_att  = (const float*)d_in[7];
  const float* gc_bias = (const float*)d_in[8];
  const float* gi_wl   = (const float*)d_in[9];
  const float* gi_bl   = (const float*)d_in[10];
  const float* gi_wr   = (const float*)d_in[11];
  const float* gi_br   = (const float*)d_in[12];
  const float* gi_att  = (const float*)d_in[13];
  const float* gi_bias = (const float*)d_in[14];
  // d_in[15]=q_w, d_in[16]=q_b: cancel out of the forward value (seq_len 1)
  const float* ctx_w   = (const float*)d_in[17];
  const float* ctx_b   = (const float*)d_in[18];
  const float* wv      = (const float*)d_in[19];
  const float* bv      = (const float*)d_in[20];
  const float* wo      = (const float*)d_in[21];
  const float* bo      = (const float*)d_in[22];
  const float* ln1_g   = (const float*)d_in[23];
  const float* ln1_b   = (const float*)d_in[24];
  const float* ln2_g   = (const float*)d_in[25];
  const float* ln2_b   = (const float*)d_in[26];
  const float* gw_w    = (const float*)d_in[27];
  const float* gw_b    = (const float*)d_in[28];
  const float* temp    = (const float*)d_in[29];
  float* out = (float*)d_out;

  // ---- workspace layout (f32 units). R1,R2,R3 are 4.19M f32 each. ----
  // Order: prep1, gemmT1, gemmW3, prep2, gemm_xlr, dist, mr_gat, gemm_attn, epi
  // R1: T1 (gemmT1->gemmW3) -> xlrh bf16 16MiB (gemm_xlr->mr_gat) -> attnb head
  // R2: pck 16MiB (dist->mr_gat) -> attnb tail
  // R3: Xh+wlrh (prep1 -> gemm_xlr/dist) -> ctxh (mr_gat->gemm_attn)
  // R4: x2, w3h, t1b, bp, bb, xlc, xrc, cmean (no overlays)
  float* ws  = (float*)d_ws;
  float* R1  = ws;
  float* R2  = R1 + (size_t)NN * OD;
  float* R3  = R2 + (size_t)NN * OD;
  float* R4  = R3 + (size_t)NN * OD;

  // R4 sublayout
  float* x2    = R4;                                   // 8192
  ushort* w3h  = (ushort*)(x2 + NN);                   // 768*512 bf16
  float* t1b   = (float*)(w3h + (size_t)HIDD * OD);    // 768
  float* bp    = t1b + HIDD;                           // 768
  float* bb    = bp + HIDD;                            // 1024 stacked bias
  float* xlc   = bb + 2 * OD;                          // 18*512
  float* xrc   = xlc + NCLS * OD;                      // 18*512
  float* cmean = xrc + NCLS * OD;                      // 512

  // aliases
  float* T1     = R1;                                  // 768*512 f32
  ushort* xlrh  = (ushort*)R1;                         // 8192*1024 bf16 = 16 MiB
  float* attnb  = R1;                                  // 8192*768 f32 (R1+R2 head)
  unsigned* pck = (unsigned*)R2;                       // [8192][64][8] u32 = 16 MiB
  ushort* Xh    = (ushort*)R3;                         // 8192*768 bf16
  ushort* wlrh  = (ushort*)(R3 + (size_t)NN * HIDD / 2);// 1024*768 bf16 stacked wl|wr
  ushort* ctxh  = (ushort*)R3;                         // 8192*512 bf16 (Xh dead)

  // 1) independent preamble tasks
  prep1_kernel<<<2895, 256, 0, stream>>>(X, Xh, x2, gi_wl, gi_wr, wlrh,
      cemb, gc_wl, gc_bl, gc_wr, gc_br, xlc, xrc,
      wv, ctx_b, bv, t1b, gi_bl, gi_br, bb);
  // 2) T1 = wv @ ctx_w (tiled fp32; T1 in R1)
  gemm_nn_f32<<<dim3(HIDD / 64, OD / 64), 256, 0, stream>>>(wv, ctx_w, T1, nullptr, HIDD, OD, HIDD);
  // 3) w3h = bf16(wo @ T1)
  gemm_nn_f32<<<dim3(HIDD / 64, OD / 64), 256, 0, stream>>>(wo, T1, nullptr, w3h, HIDD, OD, HIDD);
  // 4) bp + class GAT
  prep2_kernel<<<4, 256, 0, stream>>>(wo, t1b, bo, bp, cei, xlc, xrc, gc_att, gc_bias, cmean);
  // 5) fused xl|xr projection -> bf16 (T1 dead; xlrh into R1)
  gemm_nt_mfma<<<dim3(NN / 128, (2 * OD) / 128), 256, 0, stream>>>(Xh, wlrh, bb, nullptr, xlrh, 2 * OD, HIDD);
  // 6) kNN approx pass: symmetric MFMA, triangular grid (round-11 proven scan)
  dist_sym_mfma<<<2080, 256, 0, stream>>>(Xh, x2, pck);
  // 7) fused merge + exact refine + GAT aggregate -> ctxh bf16 (Xh dead after)
  mr_gat_kernel<<<NN, 256, 0, stream>>>(X, x2, pck, xlrh, gi_att, gi_bias, cmean, ctxh);
  // 8) attn = ctxh @ w3h^T + bp (xlrh/pck dead; attnb overlays R1+R2)
  gemm_nt_mfma<<<dim3(NN / 128, HIDD / 128), 256, 0, stream>>>(ctxh, w3h, bp, attnb, nullptr, HIDD, OD);
  // 9) LN -> LN -> GELU -> classifier
  epilogue_kernel<<<NN, 256, 0, stream>>>(X, attnb, ln1_g, ln1_b, ln2_g, ln2_b, gw_w, gw_b, temp, out);
}

// Round 15
// 630.270 us; speedup vs baseline: 1.2483x; 1.2483x over previous
//
#include <hip/hip_runtime.h>
#include <hip/hip_bf16.h>
#include <hip/hip_fp16.h>
#include <math.h>

#define NN 8192
#define HIDD 768
#define NCLS 18
#define OD 512          // HEADS*GD = 2*256
#define ETOT 342        // 324 class edges + 18 self loops
#define NEG 0.2f
#define LN_EPS 1e-5f

typedef __attribute__((ext_vector_type(8))) short bf16x8;
typedef __attribute__((ext_vector_type(4))) float f32x4;

// ---------- sorted top-5 insert (static indices, stays in registers) --------
__device__ __forceinline__ void top5_insert(float s, int idx,
    float& d0, float& d1, float& d2, float& d3, float& d4,
    int& i0, int& i1, int& i2, int& i3, int& i4) {
  if (s >= d4) return;
  if (s < d3) {
    d4 = d3; i4 = i3;
    if (s < d2) {
      d3 = d2; i3 = i2;
      if (s < d1) {
        d2 = d1; i2 = i1;
        if (s < d0) { d1 = d0; i1 = i0; d0 = s; i0 = idx; }
        else        { d1 = s;  i1 = idx; }
      } else { d2 = s; i2 = idx; }
    } else { d3 = s; i3 = idx; }
  } else { d4 = s; i4 = idx; }
}

// ---------- top-8 insert on packed u32 keys (rank-based, static indices) ----
__device__ __forceinline__ void top8k_insert(unsigned key, unsigned (&kk)[8]) {
  if (key >= kk[7]) return;
  int rank = 0;
  #pragma unroll
  for (int k = 0; k < 7; ++k) rank += (key >= kk[k]) ? 1 : 0;
  #pragma unroll
  for (int k = 7; k >= 1; --k) if (k > rank) kk[k] = kk[k-1];
  #pragma unroll
  for (int k = 0; k < 8; ++k) if (k == rank) kk[k] = key;
}

// ---------- async global->LDS 16B -------------------------------------------
__device__ __forceinline__ void stage16(const void* g, void* l) {
  __builtin_amdgcn_global_load_lds(
      (const __attribute__((address_space(1))) unsigned int*)g,
      (__attribute__((address_space(3))) unsigned int*)l, 16, 0, 0);
}

__device__ __forceinline__ ushort f2b(float v) {
  __hip_bfloat16 b = __float2bfloat16(v);
  return *(ushort*)&b;
}
__device__ __forceinline__ float b2f(ushort u) {
  unsigned uv = ((unsigned)u) << 16;
  return *(float*)&uv;
}

// ============ device body: tiled fp32 NN GEMM tile =============================
// C[M,N] = A[M,K] @ B[K,N]; one 64x64 tile at (r0,c0). buf >= 16768 B.
__device__ __forceinline__ void gemm_nn_body(const float* __restrict__ A,
    const float* __restrict__ B, float* __restrict__ Cf, ushort* __restrict__ Ch,
    int M, int N, int K, int r0, int c0, char* buf, int tid) {
  float* As = (float*)buf;                 // [64][33]
  float* Bs = (float*)(buf + 8448);        // [32][65]
  const int tx = tid & 15, ty = tid >> 4;
  float acc[4][4] = {};
  for (int kt = 0; kt < K; kt += 32) {
    __syncthreads();
    #pragma unroll
    for (int l = 0; l < 8; ++l) {
      const int idx = l * 256 + tid;
      const int m = idx >> 5, k = idx & 31;
      As[m * 33 + k] = A[(size_t)(r0 + m) * K + kt + k];
      const int k2 = idx >> 6, n = idx & 63;
      Bs[k2 * 65 + n] = B[(size_t)(kt + k2) * N + c0 + n];
    }
    __syncthreads();
    #pragma unroll
    for (int k = 0; k < 32; ++k) {
      float a[4], b[4];
      #pragma unroll
      for (int i = 0; i < 4; ++i) a[i] = As[(ty * 4 + i) * 33 + k];
      #pragma unroll
      for (int j = 0; j < 4; ++j) b[j] = Bs[k * 65 + tx * 4 + j];
      #pragma unroll
      for (int i = 0; i < 4; ++i)
        #pragma unroll
        for (int j = 0; j < 4; ++j) acc[i][j] += a[i] * b[j];
    }
  }
  #pragma unroll
  for (int i = 0; i < 4; ++i) {
    const int r = r0 + ty * 4 + i;
    #pragma unroll
    for (int j = 0; j < 4; ++j) {
      const int c = c0 + tx * 4 + j;
      if (Ch) Ch[(size_t)r * N + c] = f2b(acc[i][j]);
      else    Cf[(size_t)r * N + c] = acc[i][j];
    }
  }
}

// ============ device body: bf16 MFMA NT GEMM tile ==============================
// C = A @ B^T + bias; one 128x128 tile at (r0,c0). buf >= 32768 B.
__device__ __forceinline__ void gemm_nt_body(const ushort* __restrict__ A,
    const ushort* __restrict__ B, const float* __restrict__ bias,
    float* __restrict__ C, ushort* __restrict__ Cb, int Nc, int K,
    int r0, int c0, char* buf, int tid) {
  char* const pA = buf;
  char* const pB = buf + 16384;
  const int lane = tid & 63, wid = tid >> 6;
  const int fr = lane & 15, fq = lane >> 4;
  const int wr = (wid >> 1) * 64, wc = (wid & 1) * 64;
  f32x4 acc[4][4] = {};
  for (int kt = 0; kt < K; kt += 64) {
    __syncthreads();
    #pragma unroll
    for (int q = 0; q < 4; ++q) {
      const int chunk = wid * 256 + q * 64 + lane;
      const int row = chunk >> 3;
      const int lc = (chunk & 7) ^ (row & 7);
      const int ld = wid * 4096 + q * 1024;
      stage16((const char*)A + ((size_t)(r0 + row) * K + kt) * 2 + (size_t)lc * 16, pA + ld);
      stage16((const char*)B + ((size_t)(c0 + row) * K + kt) * 2 + (size_t)lc * 16, pB + ld);
    }
    __syncthreads();
    #pragma unroll
    for (int kk = 0; kk < 2; ++kk) {
      bf16x8 ah[4], bh[4];
      #pragma unroll
      for (int m = 0; m < 4; ++m) {
        const int ar = wr + m * 16 + fr;
        ah[m] = *(const bf16x8*)(pA + ar * 128 + (((kk * 4 + fq) ^ (ar & 7)) << 4));
      }
      #pragma unroll
      for (int n = 0; n < 4; ++n) {
        const int br = wc + n * 16 + fr;
        bh[n] = *(const bf16x8*)(pB + br * 128 + (((kk * 4 + fq) ^ (br & 7)) << 4));
      }
      #pragma unroll
      for (int m = 0; m < 4; ++m)
        #pragma unroll
        for (int n = 0; n < 4; ++n)
          acc[m][n] = __builtin_amdgcn_mfma_f32_16x16x32_bf16(ah[m], bh[n], acc[m][n], 0, 0, 0);
    }
  }
  #pragma unroll
  for (int n = 0; n < 4; ++n) {
    const int cc = c0 + wc + n * 16 + fr;
    const float bs = bias[cc];
    #pragma unroll
    for (int m = 0; m < 4; ++m) {
      #pragma unroll
      for (int j = 0; j < 4; ++j) {
        const int rr = r0 + wr + m * 16 + fq * 4 + j;
        const float val = acc[m][n][j] + bs;
        if (Cb) Cb[(size_t)rr * Nc + cc] = f2b(val);
        else    C[(size_t)rr * Nc + cc] = val;
      }
    }
  }
}

// ============ device body: symmetric dist tile (round-11 proven scan) ========
// buf >= 33792 B: [0,32768) staging/Dh/ck union; [32768,33792) x2i|x2j.
__device__ __forceinline__ void dist_body(int t, int tid,
    const ushort* __restrict__ Xh, const float* __restrict__ x2,
    unsigned* __restrict__ pck, char* buf) {
  char* const sA = buf;
  char* const sB = buf + 16384;
  __half* const Dh = (__half*)buf;
  unsigned* const ck = (unsigned*)buf;
  float* const x2i = (float*)(buf + 32768);
  float* const x2j = x2i + 128;

  int by = (int)((sqrtf(8.0f * (float)t + 1.0f) - 1.0f) * 0.5f);
  while ((by + 1) * (by + 2) / 2 <= t) ++by;
  while (by * (by + 1) / 2 > t) --by;
  const int bx = t - by * (by + 1) / 2;

  const int lane = tid & 63, wid = tid >> 6;
  const int fr = lane & 15, fq = lane >> 4;
  const int i0 = bx * 128, j0 = by * 128;
  const int wr = (wid >> 1) * 64, wc = (wid & 1) * 64;
  const bool diag = (bx == by);

  if (tid < 128) x2i[tid] = x2[i0 + tid];
  else x2j[tid - 128] = x2[j0 + tid - 128];

  f32x4 acc[4][4] = {};
  for (int kt = 0; kt < HIDD; kt += 64) {
    __syncthreads();
    #pragma unroll
    for (int q = 0; q < 4; ++q) {
      const int chunkid = q * 256 + tid;
      const int row = chunkid >> 3, cc = chunkid & 7;
      const bf16x8 va = *(const bf16x8*)(Xh + (size_t)(i0 + row) * HIDD + kt + cc * 8);
      const bf16x8 vb = *(const bf16x8*)(Xh + (size_t)(j0 + row) * HIDD + kt + cc * 8);
      const int wi = row * 128 + ((cc ^ (row & 7)) << 4);
      *(bf16x8*)(sA + wi) = va;
      *(bf16x8*)(sB + wi) = vb;
    }
    __syncthreads();
    #pragma unroll
    for (int kk = 0; kk < 2; ++kk) {
      bf16x8 bh[4];
      #pragma unroll
      for (int n = 0; n < 4; ++n) {
        const int br = wc + n * 16 + fr;
        bh[n] = *(const bf16x8*)(sB + br * 128 + (((kk * 4 + fq) ^ (br & 7)) << 4));
      }
      #pragma unroll
      for (int m = 0; m < 4; ++m) {
        const int ar = wr + m * 16 + fr;
        const bf16x8 a = *(const bf16x8*)(sA + ar * 128 + (((kk * 4 + fq) ^ (ar & 7)) << 4));
        #pragma unroll
        for (int n = 0; n < 4; ++n)
          acc[m][n] = __builtin_amdgcn_mfma_f32_16x16x32_bf16(a, bh[n], acc[m][n], 0, 0, 0);
      }
    }
  }
  __syncthreads();
  #pragma unroll
  for (int n = 0; n < 4; ++n) {
    const int col = wc + n * 16 + fr;
    #pragma unroll
    for (int m = 0; m < 4; ++m) {
      #pragma unroll
      for (int j = 0; j < 4; ++j) {
        const int row = wr + m * 16 + fq * 4 + j;
        Dh[row * 128 + ((col + row) & 127)] = __float2half(-2.0f * acc[m][n][j]);
      }
    }
  }
  __syncthreads();

  unsigned ki[8], kj[8];
  #pragma unroll
  for (int k = 0; k < 8; ++k) { ki[k] = 0xFFFFFFFFu; kj[k] = 0xFFFFFFFFu; }
  const int r = tid & 127, h = tid >> 7;
  for (int c = 0; c < 64; ++c) {
    const int col = h * 64 + c;
    const float s = x2j[col] - 768.0f + __half2float(Dh[r * 128 + ((col + r) & 127)]);
    const ushort u = __half_as_ushort(__float2half(s));
    const ushort k16 = (u & 0x8000) ? (ushort)(~u) : (ushort)(u | 0x8000);
    top8k_insert(((unsigned)k16 << 16) | (unsigned)(j0 + col), ki);
  }
  if (!diag) {
    for (int c = 0; c < 64; ++c) {
      const int cr = h * 64 + c;
      const float s = x2i[cr] - 768.0f + __half2float(Dh[cr * 128 + ((r + cr) & 127)]);
      const ushort u = __half_as_ushort(__float2half(s));
      const ushort k16 = (u & 0x8000) ? (ushort)(~u) : (ushort)(u | 0x8000);
      top8k_insert(((unsigned)k16 << 16) | (unsigned)(i0 + cr), kj);
    }
  }
  __syncthreads();
  #pragma unroll
  for (int k = 0; k < 8; ++k) ck[tid * 8 + k] = ki[k];
  __syncthreads();
  if (tid < 128) {
    unsigned mk[8];
    #pragma unroll
    for (int k = 0; k < 8; ++k) mk[k] = ck[tid * 8 + k];
    #pragma unroll
    for (int k = 0; k < 8; ++k) top8k_insert(ck[(tid + 128) * 8 + k], mk);
    const size_t base = ((size_t)(i0 + tid) * 64 + by) * 8;
    #pragma unroll
    for (int k = 0; k < 8; ++k) pck[base + k] = mk[k];
  }
  if (!diag) {
    __syncthreads();
    #pragma unroll
    for (int k = 0; k < 8; ++k) ck[tid * 8 + k] = kj[k];
    __syncthreads();
    if (tid < 128) {
      unsigned mk[8];
      #pragma unroll
      for (int k = 0; k < 8; ++k) mk[k] = ck[tid * 8 + k];
      #pragma unroll
      for (int k = 0; k < 8; ++k) top8k_insert(ck[(tid + 128) * 8 + k], mk);
      const size_t base = ((size_t)(j0 + tid) * 64 + bx) * 8;
      #pragma unroll
      for (int k = 0; k < 8; ++k) pck[base + k] = mk[k];
    }
  }
}

// ============ fused1: prep1 sections + T1 = wv @ ctx_w ========================
// blocks [0,2048) rowcast; [2048,2816) wcast; [2816,2888) class proj;
//        [2888,2891) t1b; [2891,2895) bias stack; [2895,2991) gemm T1.
__global__ __launch_bounds__(256) void fused1_kernel(
    const float* __restrict__ X, ushort* __restrict__ Xh, float* __restrict__ x2,
    const float* __restrict__ gi_wl, const float* __restrict__ gi_wr,
    ushort* __restrict__ wlrh,
    const float* __restrict__ cemb, const float* __restrict__ gc_wl,
    const float* __restrict__ gc_bl, const float* __restrict__ gc_wr,
    const float* __restrict__ gc_br, float* __restrict__ xlc, float* __restrict__ xrc,
    const float* __restrict__ wv, const float* __restrict__ ctx_b,
    const float* __restrict__ bv, float* __restrict__ t1b,
    const float* __restrict__ gi_bl, const float* __restrict__ gi_br,
    float* __restrict__ bb, const float* __restrict__ ctx_w, float* __restrict__ T1) {
  __shared__ __align__(16) char buf[16768];
  const int bx = blockIdx.x, tid = threadIdx.x;
  if (bx < 2048) {                       // ---- rowcast + rownorm ----
    const int row = bx * 4 + (tid >> 6);
    const int lane = tid & 63;
    const float4* src = (const float4*)(X + (size_t)row * HIDD);
    ushort4* dst = (ushort4*)(Xh + (size_t)row * HIDD);
    float s = 0.f;
    #pragma unroll
    for (int q = 0; q < 3; ++q) {
      float4 v = src[lane + q * 64];
      s += v.x * v.x + v.y * v.y + v.z * v.z + v.w * v.w;
      dst[lane + q * 64] = make_ushort4(f2b(v.x), f2b(v.y), f2b(v.z), f2b(v.w));
    }
    #pragma unroll
    for (int off = 32; off; off >>= 1) s += __shfl_down(s, off);
    if (lane == 0) x2[row] = s;
  } else if (bx < 2816) {                // ---- weight casts ----
    int rel = bx - 2048;
    const float* src = gi_wl; ushort* dst = wlrh;
    if (rel >= 384) { rel -= 384; src = gi_wr; dst = wlrh + (size_t)OD * HIDD; }
    const int i = rel * 256 + tid;
    float4 v = ((const float4*)src)[i];
    ((ushort4*)dst)[i] = make_ushort4(f2b(v.x), f2b(v.y), f2b(v.z), f2b(v.w));
  } else if (bx < 2888) {                // ---- class xlc/xrc ----
    int t = (bx - 2816) * 256 + tid;
    const float* W; const float* b; float* Y;
    if (t < NCLS * OD) { W = gc_wl; b = gc_bl; Y = xlc; }
    else { t -= NCLS * OD; W = gc_wr; b = gc_br; Y = xrc; }
    const int row = t / OD, o = t - row * OD;
    const float4* xr4 = (const float4*)(cemb + (size_t)row * HIDD);
    const float4* wr4 = (const float4*)(W + (size_t)o * HIDD);
    float acc = 0.f;
    for (int k = 0; k < HIDD / 4; ++k) {
      const float4 a = xr4[k], w4 = wr4[k];
      acc += a.x * w4.x + a.y * w4.y + a.z * w4.z + a.w * w4.w;
    }
    Y[t] = acc + b[o];
  } else if (bx < 2891) {                // ---- t1b ----
    const int t = (bx - 2888) * 256 + tid;
    if (t < HIDD) {
      const float4* cb4 = (const float4*)ctx_b;
      const float4* wv4 = (const float4*)(wv + (size_t)t * HIDD);
      float acc = 0.f;
      for (int k = 0; k < HIDD / 4; ++k) {
        const float4 a = cb4[k], w4 = wv4[k];
        acc += a.x * w4.x + a.y * w4.y + a.z * w4.z + a.w * w4.w;
      }
      t1b[t] = acc + bv[t];
    }
  } else if (bx < 2895) {                // ---- bias stack ----
    const int t = (bx - 2891) * 256 + tid;
    if (t < OD) bb[t] = gi_bl[t];
    else if (t < 2 * OD) bb[t] = gi_br[t - OD];
  } else {                               // ---- T1 = wv @ ctx_w ----
    const int rel = bx - 2895;           // [0,96): 12 x 8 tiles
    gemm_nn_body(wv, ctx_w, T1, nullptr, HIDD, OD, HIDD,
                 (rel >> 3) * 64, (rel & 7) * 64, buf, tid);
  }
}

// ============ fused2: dist(2080) ∪ gemm_xlr(512) ∪ gemmW3(96) ∪ prep2(4) =====
__global__ __launch_bounds__(256, 4) void fused2_kernel(
    const ushort* __restrict__ Xh, const float* __restrict__ x2,
    unsigned* __restrict__ pck,
    const ushort* __restrict__ wlrh, const float* __restrict__ bb,
    ushort* __restrict__ xlrh,
    const float* __restrict__ wo, const float* __restrict__ T1,
    ushort* __restrict__ w3h,
    const float* __restrict__ t1b, const float* __restrict__ bo,
    float* __restrict__ bp, const int* __restrict__ cei,
    const float* __restrict__ xlc, const float* __restrict__ xrc,
    const float* __restrict__ gc_att, const float* __restrict__ gc_bias,
    float* __restrict__ cmean) {
  __shared__ __align__(16) char buf[33792];
  const int bid = blockIdx.x, tid = threadIdx.x;
  if (bid < 2080) {                      // ---- dist tile ----
    dist_body(bid, tid, Xh, x2, pck, buf);
  } else if (bid < 2592) {               // ---- xlr projection ----
    const int rel = bid - 2080;          // [0,512): 64 x 8
    gemm_nt_body(Xh, wlrh, bb, nullptr, xlrh, 2 * OD, HIDD,
                 (rel >> 3) * 128, (rel & 7) * 128, buf, tid);
  } else if (bid < 2688) {               // ---- w3h = bf16(wo @ T1) ----
    const int rel = bid - 2592;          // [0,96): 12 x 8
    gemm_nn_body(wo, T1, nullptr, w3h, HIDD, OD, HIDD,
                 (rel >> 3) * 64, (rel & 7) * 64, buf, tid);
  } else if (bid < 2691) {               // ---- bp ----
    const int t = (bid - 2688) * 256 + tid;
    if (t < HIDD) {
      const float4* tb4 = (const float4*)t1b;
      const float4* wo4 = (const float4*)(wo + (size_t)t * HIDD);
      float acc = 0.f;
      for (int k = 0; k < HIDD / 4; ++k) {
        const float4 a = tb4[k], w4 = wo4[k];
        acc += a.x * w4.x + a.y * w4.y + a.z * w4.z + a.w * w4.w;
      }
      bp[t] = acc + bo[t];
    }
  } else {                               // ---- class GAT (1 block) ----
    float* sc = (float*)buf;                          // 684 f32
    int* es = (int*)(buf + 2736);                     // 342 i32
    int* ed = es + ETOT;                              // 342 i32
    float* mx = (float*)(buf + 2736 + 2736);          // [18][2]
    float* sm = mx + NCLS * 2;                        // [18][2]
    for (int e = tid; e < ETOT; e += 256) {
      if (e < 324) { es[e] = cei[e]; ed[e] = cei[324 + e]; }
      else         { es[e] = e - 324; ed[e] = e - 324; }
    }
    __syncthreads();
    const int lane = tid & 63, w = tid >> 6;
    for (int t = w; t < ETOT * 2; t += 4) {
      const int e = t >> 1, h = t & 1;
      const float* xlr = xlc + (size_t)es[e] * OD + h * 256;
      const float* xrr = xrc + (size_t)ed[e] * OD + h * 256;
      const float* ar  = gc_att + h * 256;
      float s = 0.f;
      for (int d = lane; d < 256; d += 64) {
        float v = xlr[d] + xrr[d];
        v = v > 0.f ? v : NEG * v;
        s += v * ar[d];
      }
      #pragma unroll
      for (int off = 32; off; off >>= 1) s += __shfl_down(s, off);
      if (lane == 0) sc[t] = s;
    }
    __syncthreads();
    if (tid < NCLS * 2) {
      const int d = tid >> 1, h = tid & 1;
      float m = -3e38f;
      for (int e = 0; e < ETOT; ++e) if (ed[e] == d) m = fmaxf(m, sc[e * 2 + h]);
      float ssum = 0.f;
      for (int e = 0; e < ETOT; ++e) if (ed[e] == d) ssum += expf(sc[e * 2 + h] - m);
      mx[d * 2 + h] = m; sm[d * 2 + h] = 1.f / ssum;
    }
    __syncthreads();
    for (int t = tid; t < ETOT * 2; t += 256) {
      const int e = t >> 1, h = t & 1;
      sc[t] = expf(sc[t] - mx[ed[e] * 2 + h]) * sm[ed[e] * 2 + h];
    }
    __syncthreads();
    for (int c = tid; c < OD; c += 256) {
      const int h = c >> 8;
      float acc = 0.f;
      for (int e = 0; e < ETOT; ++e) acc += sc[e * 2 + h] * xlc[(size_t)es[e] * OD + c];
      cmean[c] = acc * (1.f / 18.f) + gc_bias[c];
    }
  }
}

// ---------- fused: butterfly merge + exact refine + GATv2 aggregate ----------
__global__ __launch_bounds__(256) void mr_gat_kernel(
    const float* __restrict__ X, const float* __restrict__ x2,
    const unsigned* __restrict__ pck, const ushort* __restrict__ xlrh,
    const float* __restrict__ att, const float* __restrict__ bias,
    const float* __restrict__ cmean, ushort* __restrict__ ctxh) {
  __shared__ float rows[7][512];
  __shared__ float rsc[8];
  __shared__ int rcand[8];
  __shared__ int nbr[6];
  __shared__ float sc[12];
  __shared__ float alpha[12];
  const int i = blockIdx.x;
  const int tid = threadIdx.x;
  const int lane = tid & 63, w = tid >> 6;

  if (w == 0) {                            // merge 64 per-tile top-8 lists
    unsigned mk[8];
    #pragma unroll
    for (int k = 0; k < 8; ++k) mk[k] = pck[(size_t)i * 512 + lane * 8 + k];
    #pragma unroll
    for (int st = 1; st < 64; st <<= 1) {
      unsigned ok[8];
      #pragma unroll
      for (int k = 0; k < 8; ++k) ok[k] = __shfl_xor(mk[k], st);
      #pragma unroll
      for (int k = 0; k < 8; ++k) top8k_insert(ok[k], mk);
    }
    if (lane < 8) rcand[lane] = (int)(mk[lane] & 0xFFFFu);
  } else {                                 // preload self xl (rows[5]) + xr (rows[6])
    const int tt = tid - 64;
    if (tt < 128) {
      const int rr = 5 + (tt >> 6), e4 = tt & 63;
      const bf16x8 v = *(const bf16x8*)(xlrh + (size_t)i * 1024 + (rr == 6 ? 512 : 0) + e4 * 8);
      #pragma unroll
      for (int j = 0; j < 8; ++j) rows[rr][e4 * 8 + j] = b2f((ushort)v[j]);
    }
  }
  __syncthreads();
  // exact fp32 refine: wave w handles candidates 2w (lanes 0-31) and 2w+1
  {
    const int cnd = w * 2 + (lane >> 5);
    const int sl = lane & 31;
    const int cidx = rcand[cnd];
    const float4* xi = (const float4*)(X + (size_t)i * HIDD);
    const float4* xc = (const float4*)(X + (size_t)cidx * HIDD);
    float acc = 0.f;
    #pragma unroll
    for (int q = 0; q < 6; ++q) {
      const float4 a = xi[sl + q * 32];
      const float4 b = xc[sl + q * 32];
      acc += a.x * b.x + a.y * b.y + a.z * b.z + a.w * b.w;
    }
    #pragma unroll
    for (int off = 16; off; off >>= 1) acc += __shfl_down(acc, off, 32);
    if (sl == 0) rsc[cnd] = x2[cidx] - 2.0f * acc;
  }
  __syncthreads();
  if (tid == 0) {                          // exact top-5 of the 8 candidates
    float d0 = 3e38f, d1 = 3e38f, d2 = 3e38f, d3 = 3e38f, d4 = 3e38f;
    int i0 = 0, i1 = 0, i2 = 0, i3 = 0, i4 = 0;
    #pragma unroll
    for (int k = 0; k < 8; ++k)
      top5_insert(rsc[k], rcand[k], d0, d1, d2, d3, d4, i0, i1, i2, i3, i4);
    nbr[0] = i0; nbr[1] = i1; nbr[2] = i2; nbr[3] = i3; nbr[4] = i4; nbr[5] = i;
  }
  __syncthreads();
  // gather 5 neighbor xl rows (bf16): 320 slots over 256 threads -> strided loop
  for (int t2 = tid; t2 < 5 * 64; t2 += 256) {
    const int rr = t2 >> 6, e4 = t2 & 63;
    const bf16x8 v = *(const bf16x8*)(xlrh + (size_t)nbr[rr] * 1024 + e4 * 8);
    #pragma unroll
    for (int j = 0; j < 8; ++j) rows[rr][e4 * 8 + j] = b2f((ushort)v[j]);
  }
  __syncthreads();
  // GATv2 scores (12 tasks over 4 waves)
  for (int t = w; t < 12; t += 4) {
    const int e = t >> 1, h = t & 1;
    const float* ar = att + h * 256;
    float s = 0.f;
    #pragma unroll
    for (int q = 0; q < 4; ++q) {
      const int d = lane + q * 64;
      float v = rows[e][h * 256 + d] + rows[6][h * 256 + d];
      v = v > 0.f ? v : NEG * v;
      s += v * ar[d];
    }
    #pragma unroll
    for (int off = 32; off; off >>= 1) s += __shfl_down(s, off);
    if (lane == 0) sc[t] = s;
  }
  __syncthreads();
  if (tid < 2) {
    const int h = tid;
    float m = -3e38f;
    #pragma unroll
    for (int e = 0; e < 6; ++e) m = fmaxf(m, sc[e * 2 + h]);
    float ssum = 0.f;
    #pragma unroll
    for (int e = 0; e < 6; ++e) { float ex = expf(sc[e * 2 + h] - m); alpha[e * 2 + h] = ex; ssum += ex; }
    const float inv = 1.f / ssum;
    #pragma unroll
    for (int e = 0; e < 6; ++e) alpha[e * 2 + h] *= inv;
  }
  __syncthreads();
  for (int c = tid; c < OD; c += 256) {
    const int h = c >> 8;
    float acc = 0.f;
    #pragma unroll
    for (int e = 0; e < 6; ++e) acc += alpha[e * 2 + h] * rows[e][c];
    ctxh[(size_t)i * OD + c] = f2b(acc + bias[c] + cmean[c]);
  }
}

// ---------- standalone bf16 MFMA NT GEMM (attn chain) ------------------------
__global__ __launch_bounds__(256) void gemm_nt_mfma(const ushort* __restrict__ A,
    const ushort* __restrict__ B, const float* __restrict__ bias,
    float* __restrict__ C, ushort* __restrict__ Cb, int Nc, int K) {
  __shared__ __align__(16) char lds[32768];
  gemm_nt_body(A, B, bias, C, Cb, Nc, K, blockIdx.x * 128, blockIdx.y * 128,
               lds, threadIdx.x);
}

// ---------- fused epilogue: LN1 -> LN2 -> GELU -> 18-way classifier ----------
__global__ __launch_bounds__(256) void epilogue_kernel(const float* __restrict__ inst,
    const float* __restrict__ attn, const float* __restrict__ g1, const float* __restrict__ b1,
    const float* __restrict__ g2, const float* __restrict__ b2, const float* __restrict__ gw,
    const float* __restrict__ gb, const float* __restrict__ temp, float* __restrict__ out) {
  __shared__ float buf[HIDD];
  __shared__ float red[4];
  const int i = blockIdx.x;
  const int tid = threadIdx.x;
  const int lane = tid & 63, w = tid >> 6;
  size_t base = (size_t)i * HIDD;
  float v0 = inst[base + tid]       + attn[base + tid];
  float v1 = inst[base + tid + 256] + attn[base + tid + 256];
  float v2 = inst[base + tid + 512] + attn[base + tid + 512];

  float s = v0 + v1 + v2;
  #pragma unroll
  for (int off = 32; off; off >>= 1) s += __shfl_down(s, off);
  if (lane == 0) red[w] = s;
  __syncthreads();
  float mean = (red[0] + red[1] + red[2] + red[3]) * (1.f / HIDD);
  __syncthreads();
  float e0 = v0 - mean, e1 = v1 - mean, e2 = v2 - mean;
  s = e0 * e0 + e1 * e1 + e2 * e2;
  #pragma unroll
  for (int off = 32; off; off >>= 1) s += __shfl_down(s, off);
  if (lane == 0) red[w] = s;
  __syncthreads();
  float rstd = rsqrtf((red[0] + red[1] + red[2] + red[3]) * (1.f / HIDD) + LN_EPS);
  __syncthreads();
  float y0 = e0 * rstd * g1[tid]       + b1[tid];
  float y1 = e1 * rstd * g1[tid + 256] + b1[tid + 256];
  float y2 = e2 * rstd * g1[tid + 512] + b1[tid + 512];

  s = y0 + y1 + y2;
  #pragma unroll
  for (int off = 32; off; off >>= 1) s += __shfl_down(s, off);
  if (lane == 0) red[w] = s;
  __syncthreads();
  float mean2 = (red[0] + red[1] + red[2] + red[3]) * (1.f / HIDD);
  __syncthreads();
  float f0 = y0 - mean2, f1 = y1 - mean2, f2 = y2 - mean2;
  s = f0 * f0 + f1 * f1 + f2 * f2;
  #pragma unroll
  for (int off = 32; off; off >>= 1) s += __shfl_down(s, off);
  if (lane == 0) red[w] = s;
  __syncthreads();
  float rstd2 = rsqrtf((red[0] + red[1] + red[2] + red[3]) * (1.f / HIDD) + LN_EPS);
  float z0 = f0 * rstd2 * g2[tid]       + b2[tid];
  float z1 = f1 * rstd2 * g2[tid + 256] + b2[tid + 256];
  float z2 = f2 * rstd2 * g2[tid + 512] + b2[tid + 512];
  buf[tid]       = 0.5f * z0 * (1.f + erff(z0 * 0.70710678118654752f));
  buf[tid + 256] = 0.5f * z1 * (1.f + erff(z1 * 0.70710678118654752f));
  buf[tid + 512] = 0.5f * z2 * (1.f + erff(z2 * 0.70710678118654752f));
  __syncthreads();

  float invT = 1.f / temp[0];
  for (int c = w; c < NCLS; c += 4) {
    const float* wr = gw + (size_t)c * HIDD;
    float acc = 0.f;
    for (int d = lane; d < HIDD; d += 64) acc += buf[d] * wr[d];
    #pragma unroll
    for (int off = 32; off; off >>= 1) acc += __shfl_down(acc, off);
    if (lane == 0) out[(size_t)i * NCLS + c] = (acc + gb[c]) * invT;
  }
}

// ---------------------------------------------------------------------------
extern "C" void kernel_launch(void* const* d_in, const int* in_sizes, int n_in,
                              void* d_out, int out_size, void* d_ws, size_t ws_size,
                              hipStream_t stream) {
  (void)in_sizes; (void)n_in; (void)out_size; (void)ws_size;
  const float* X       = (const float*)d_in[0];
  const int*   cei     = (const int*)  d_in[1];
  const float* cemb    = (const float*)d_in[2];
  const float* gc_wl   = (const float*)d_in[3];
  const float* gc_bl   = (const float*)d_in[4];
  const float* gc_wr   = (const float*)d_in[5];
  const float* gc_br   = (const float*)d_in[6];
  const float* gc_att  = (const float*)d_in[7];
  const float* gc_bias = (const float*)d_in[8];
  const float* gi_wl   = (const float*)d_in[9];
  const float* gi_bl   = (const float*)d_in[10];
  const float* gi_wr   = (const float*)d_in[11];
  const float* gi_br   = (const float*)d_in[12];
  const float* gi_att  = (const float*)d_in[13];
  const float* gi_bias = (const float*)d_in[14];
  // d_in[15]=q_w, d_in[16]=q_b: cancel out of the forward value (seq_len 1)
  const float* ctx_w   = (const float*)d_in[17];
  const float* ctx_b   = (const float*)d_in[18];
  const float* wv      = (const float*)d_in[19];
  const float* bv      = (const float*)d_in[20];
  const float* wo      = (const float*)d_in[21];
  const float* bo      = (const float*)d_in[22];
  const float* ln1_g   = (const float*)d_in[23];
  const float* ln1_b   = (const float*)d_in[24];
  const float* ln2_g   = (const float*)d_in[25];
  const float* ln2_b   = (const float*)d_in[26];
  const float* gw_w    = (const float*)d_in[27];
  const float* gw_b    = (const float*)d_in[28];
  const float* temp    = (const float*)d_in[29];
  float* out = (float*)d_out;

  // ---- workspace layout (f32 units). R1,R2,R3 are 4.19M f32 each. ----
  // Order: fused1, fused2, mr_gat, gemm_attn, epilogue
  // R1: T1 (fused1->fused2) -> xlrh bf16 16MiB (fused2->mr_gat) -> attnb head
  //     [T1 lives in R1 head; xlrh written by fused2 AFTER T1's last read
  //      (w3h-fold blocks) -- both in fused2; w3h blocks read T1 while xlr
  //      blocks write xlrh over the same region! CONFLICT -> put T1 in R4.]
  // R2: pck 16MiB (fused2->mr_gat) -> attnb tail
  // R3: Xh+wlrh (fused1 -> fused2) -> ctxh (mr_gat->gemm_attn)
  // R4: x2, w3h, t1b, bp, bb, xlc, xrc, cmean, T1 (no overlays)
  float* ws  = (float*)d_ws;
  float* R1  = ws;
  float* R2  = R1 + (size_t)NN * OD;
  float* R3  = R2 + (size_t)NN * OD;
  float* R4  = R3 + (size_t)NN * OD;

  // R4 sublayout
  float* x2    = R4;                                   // 8192
  ushort* w3h  = (ushort*)(x2 + NN);                   // 768*512 bf16
  float* t1b   = (float*)(w3h + (size_t)HIDD * OD);    // 768
  float* bp    = t1b + HIDD;                           // 768
  float* bb    = bp + HIDD;                            // 1024 stacked bias
  float* xlc   = bb + 2 * OD;                          // 18*512
  float* xrc   = xlc + NCLS * OD;                      // 18*512
  float* cmean = xrc + NCLS * OD;                      // 512
  float* T1    = cmean + OD;                           // 768*512 f32 (1.5 MiB)

  // aliases
  ushort* xlrh  = (ushort*)R1;                         // 8192*1024 bf16 = 16 MiB
  float* attnb  = R1;                                  // 8192*768 f32 (R1+R2 head)
  unsigned* pck = (unsigned*)R2;                       // [8192][64][8] u32 = 16 MiB
  ushort* Xh    = (ushort*)R3;                         // 8192*768 bf16
  ushort* wlrh  = (ushort*)(R3 + (size_t)NN * HIDD / 2);// 1024*768 bf16 stacked wl|wr
  ushort* ctxh  = (ushort*)R3;                         // 8192*512 bf16 (Xh dead)

  // 1) all input-only preamble tasks (incl. T1 = wv @ ctx_w)
  fused1_kernel<<<2991, 256, 0, stream>>>(X, Xh, x2, gi_wl, gi_wr, wlrh,
      cemb, gc_wl, gc_bl, gc_wr, gc_br, xlc, xrc,
      wv, ctx_b, bv, t1b, gi_bl, gi_br, bb, ctx_w, T1);
  // 2) dist ∪ xlr-projection ∪ w3h-fold ∪ (bp + class GAT) — all depend
  //    only on fused1 outputs (T1 now in R4, disjoint from xlrh)
  fused2_kernel<<<2692, 256, 0, stream>>>(Xh, x2, pck, wlrh, bb, xlrh,
      wo, T1, w3h, t1b, bo, bp, cei, xlc, xrc, gc_att, gc_bias, cmean);
  // 3) fused merge + exact refine + GAT aggregate -> ctxh bf16 (Xh dead after)
  mr_gat_kernel<<<NN, 256, 0, stream>>>(X, x2, pck, xlrh, gi_att, gi_bias, cmean, ctxh);
  // 4) attn = ctxh @ w3h^T + bp (xlrh/pck dead; attnb overlays R1+R2)
  gemm_nt_mfma<<<dim3(NN / 128, HIDD / 128), 256, 0, stream>>>(ctxh, w3h, bp, attnb, nullptr, HIDD, OD);
  // 5) LN -> LN -> GELU -> classifier
  epilogue_kernel<<<NN, 256, 0, stream>>>(X, attnb, ln1_g, ln1_b, ln2_g, ln2_b, gw_w, gw_b, temp, out);
}